// Round 3
// baseline (1297.304 us; speedup 1.0000x reference)
//
#include <hip/hip_runtime.h>
#include <hip/hip_bf16.h>

#define N_NODES 50000
#define N_EDGES 800000
#define FEAT    128
#define N_TILES (N_NODES / 16)          // 3125
#define GEMM_BLOCKS 784                  // 782 needed (3125/4), padded to mult of 8
#define MAXD    32                       // slots per node; Poisson(16) P(deg>=32)~1e-4
#define OVF_CAP 16384
#define NODES_PER_GRP 6250               // 50000 / 8
#define CHUNK   2048
#define NCHUNK  ((N_EDGES + CHUNK - 1) / CHUNK)   // 391
#define QCAP    110000                   // per-group queue capacity (mean 100K, sigma~296)
#define SCAT_BPG 98                      // scatter blocks per group -> 784 total

using short8  = __attribute__((ext_vector_type(8))) short;
using float4v = __attribute__((ext_vector_type(4))) float;

// ---------------- workspace layout (bytes) ----------------
// flag[16 ints] @0   (flag[1]=ovf cursor, flag[8..15]=per-group queue cursors)
// fill int[50048] @64 | ovf int2[16384] @200256 | slots uint[50000*32] @331328
// hidden ushort[50000*128] @6731328 | queue int2[8*QCAP] @19531328   total ~26.6 MB

__device__ __forceinline__ unsigned short f2b(float f) {
    __hip_bfloat16 h = __float2bfloat16(f);           // RNE
    return __builtin_bit_cast(unsigned short, h);
}

// k1: blocks [0,GEMM_BLOCKS) = GEMM (LDS-staged W, proven R1 path).
//     blocks [GEMM_BLOCKS, +NCHUNK) = partition pass: read each edge ONCE
//     (coalesced), append (dst, rec) to its XCD-group queue via wave-aggregated
//     atomics. Replaces the old 8x-redundant scan + scattered slot stores.
__global__ __launch_bounds__(256) void k_fused(const float* __restrict__ x,
                                               const float* __restrict__ W,
                                               const float* __restrict__ bias,
                                               unsigned short* __restrict__ hidden,
                                               const int* __restrict__ ei,
                                               const float* __restrict__ wt,
                                               int* __restrict__ flag,
                                               int2* __restrict__ queue) {
    __shared__ __align__(16) unsigned short Wlds[128 * 136];
    const int t = threadIdx.x;

    if (blockIdx.x < GEMM_BLOCKS) {
        // ---------------- GEMM path (R1-proven) ----------------
        for (int j = 0; j < 16; ++j) {
            int idx4 = j * 256 + t;
            float4v wv = *(const float4v*)(W + (size_t)idx4 * 4);
            int r = (idx4 * 4) >> 7;
            int c = (idx4 * 4) & 127;
            unsigned short* p = &Wlds[r * 136 + c];
            p[0] = f2b(wv[0]); p[1] = f2b(wv[1]); p[2] = f2b(wv[2]); p[3] = f2b(wv[3]);
        }
        __syncthreads();

        const int wave = t >> 6;
        const int lane = t & 63;
        int tile = blockIdx.x * 4 + wave;
        if (tile >= N_TILES) tile = N_TILES - 1;    // clamp: redundant work, no divergent exit
        const int rowBase = tile * 16;
        const int m    = lane & 15;
        const int quad = lane >> 4;

        float4v acc[8];
        #pragma unroll
        for (int i = 0; i < 8; ++i) acc[i] = (float4v){0.f, 0.f, 0.f, 0.f};

        for (int kk = 0; kk < 4; ++kk) {
            const int k0 = kk * 32 + quad * 8;
            const float* ap = x + (size_t)(rowBase + m) * FEAT + k0;
            float4v a0 = *(const float4v*)(ap);
            float4v a1 = *(const float4v*)(ap + 4);
            short8 af;
            #pragma unroll
            for (int j = 0; j < 4; ++j) { af[j] = (short)f2b(a0[j]); af[4 + j] = (short)f2b(a1[j]); }
            #pragma unroll
            for (int nt = 0; nt < 8; ++nt) {
                short8 bf = *(const short8*)&Wlds[(nt * 16 + m) * 136 + k0];
                acc[nt] = __builtin_amdgcn_mfma_f32_16x16x32_bf16(af, bf, acc[nt], 0, 0, 0);
            }
        }

        const int r0 = rowBase + quad * 4;          // C/D: col=lane&15, row=quad*4+r
        for (int nt = 0; nt < 8; ++nt) {
            const int col = nt * 16 + m;
            const float bc = bias[col];
            #pragma unroll
            for (int r = 0; r < 4; ++r) {
                hidden[(size_t)(r0 + r) * FEAT + col] = f2b(acc[nt][r] + bc);
            }
        }
    } else {
        // ---------------- partition pass ----------------
        const int bid  = blockIdx.x - GEMM_BLOCKS;   // chunk id, 0..390
        const int lane = t & 63;

        // per-wave int64-vs-int32 detection (int64: odd words of first 64 are 0)
        unsigned long long mball = __ballot(ei[2 * lane + 1] != 0);
        const int sh = (mball == 0ULL) ? 1 : 0;

        int* qcnt = flag + 8;
        const int e0 = bid * CHUNK + t;

        #pragma unroll
        for (int i = 0; i < 8; ++i) {
            int e = e0 + i * 256;
            const bool valid = e < N_EDGES;
            int g = 8;                               // sentinel: matches no group
            int dst = 0; unsigned rec = 0;
            if (valid) {
                dst = ei[(size_t)e << sh];
                if ((unsigned)dst >= N_NODES) dst = 0;
                int src = ei[(size_t)(N_EDGES + e) << sh];
                if ((unsigned)src >= N_NODES) src = 0;
                rec = ((unsigned)f2b(wt[e]) << 16) | (unsigned)src;
                g = dst / NODES_PER_GRP;             // 0..7
            }
            #pragma unroll
            for (int gg = 0; gg < 8; ++gg) {
                unsigned long long mask = __ballot(g == gg);
                if (g == gg) {
                    int leader = __ffsll((unsigned long long)mask) - 1;
                    int prefix = __popcll(mask & ((1ULL << lane) - 1ULL));
                    int base = 0;
                    if (lane == leader) base = atomicAdd(&qcnt[gg], __popcll(mask));
                    base = __shfl(base, leader, 64);
                    int idx = base + prefix;
                    if (idx < QCAP) {
                        int2 r; r.x = dst; r.y = (int)rec;
                        queue[(size_t)gg * QCAP + idx] = r;
                    }
                }
            }
        }
    }
}

// k2: XCD-local scatter. Group g's blocks read ONLY queue[g] (~800KB, coalesced);
// fill/slot atomics+stores hit an 800KB region resident in that XCD's L2.
__global__ __launch_bounds__(256) void k_scat(const int* __restrict__ flagq,
                                              const int2* __restrict__ queue,
                                              int* __restrict__ flag,
                                              int* __restrict__ fill,
                                              unsigned int* __restrict__ slots,
                                              int2* __restrict__ ovf) {
    const int g = blockIdx.x & 7;                    // == XCD (round-robin dispatch)
    const int b = blockIdx.x >> 3;                   // 0..SCAT_BPG-1
    int n = flagq[8 + g]; if (n > QCAP) n = QCAP;
    const int2* q = queue + (size_t)g * QCAP;

    for (int i = b * 256 + (int)threadIdx.x; i < n; i += SCAT_BPG * 256) {
        int2 ent = q[i];
        int dst = ent.x;
        int pos = atomicAdd(&fill[dst], 1);
        if (pos < MAXD) {
            slots[(size_t)dst * MAXD + pos] = (unsigned int)ent.y;
        } else {
            int op = atomicAdd(&flag[1], 1);
            if (op < OVF_CAP) { int2 r; r.x = dst; r.y = ent.y; ovf[op] = r; }
        }
    }
}

// out[node][:] = sum_slots w_e * hidden[src_e][:]
// wave per node; lane-group g (16 lanes) handles edge e+g; each lane loads 16B
// (8 bf16 feats). 2x unrolled: two slot-lines + two gathers in flight.
__global__ __launch_bounds__(256) void k_agg(const int* __restrict__ fill,
                                             const unsigned int* __restrict__ slots,
                                             const unsigned int* __restrict__ hid,
                                             const int* __restrict__ flag,
                                             const int2* __restrict__ ovf,
                                             float* __restrict__ out) {
    const int wave = threadIdx.x >> 6;
    const int lane = threadIdx.x & 63;
    const int node = blockIdx.x * 4 + wave;         // grid exact: 12500*4 = 50000
    const int grp  = lane >> 4;
    const int sub  = lane & 15;

    const int degf = fill[node];
    const int deg  = (degf > MAXD) ? MAXD : degf;
    const uint4* sl4 = (const uint4*)(slots + (size_t)node * MAXD);  // 8 lines

    float acc[8];
    #pragma unroll
    for (int j = 0; j < 8; ++j) acc[j] = 0.f;

    const int iters = (deg + 3) >> 2;               // <= 8
    for (int it = 0; it < iters; it += 2) {
        uint4 ra = sl4[it];
        uint4 rb = sl4[it | 1];                     // <=7: always in-bounds
        unsigned reca = (grp < 2) ? (grp == 0 ? ra.x : ra.y)
                                  : (grp == 2 ? ra.z : ra.w);
        unsigned recb = (grp < 2) ? (grp == 0 ? rb.x : rb.y)
                                  : (grp == 2 ? rb.z : rb.w);
        const int  ea = it * 4 + grp;
        const int  eb = ea + 4;
        const bool va = ea < deg;
        const bool vb = eb < deg;
        const float wa = va ? __uint_as_float(reca & 0xffff0000u) : 0.f;
        const float wb = vb ? __uint_as_float(recb & 0xffff0000u) : 0.f;
        const unsigned sa = va ? (reca & 0xffffu) : 0u;
        const unsigned sb = vb ? (recb & 0xffffu) : 0u;
        uint4 ha = *((const uint4*)(hid + (size_t)sa * 64) + sub);  // 16B/lane gather
        uint4 hb = *((const uint4*)(hid + (size_t)sb * 64) + sub);
        acc[0] = fmaf(wa, __uint_as_float((ha.x & 0xffffu) << 16), acc[0]);
        acc[1] = fmaf(wa, __uint_as_float(ha.x & 0xffff0000u),     acc[1]);
        acc[2] = fmaf(wa, __uint_as_float((ha.y & 0xffffu) << 16), acc[2]);
        acc[3] = fmaf(wa, __uint_as_float(ha.y & 0xffff0000u),     acc[3]);
        acc[4] = fmaf(wa, __uint_as_float((ha.z & 0xffffu) << 16), acc[4]);
        acc[5] = fmaf(wa, __uint_as_float(ha.z & 0xffff0000u),     acc[5]);
        acc[6] = fmaf(wa, __uint_as_float((ha.w & 0xffffu) << 16), acc[6]);
        acc[7] = fmaf(wa, __uint_as_float(ha.w & 0xffff0000u),     acc[7]);
        acc[0] = fmaf(wb, __uint_as_float((hb.x & 0xffffu) << 16), acc[0]);
        acc[1] = fmaf(wb, __uint_as_float(hb.x & 0xffff0000u),     acc[1]);
        acc[2] = fmaf(wb, __uint_as_float((hb.y & 0xffffu) << 16), acc[2]);
        acc[3] = fmaf(wb, __uint_as_float(hb.y & 0xffff0000u),     acc[3]);
        acc[4] = fmaf(wb, __uint_as_float((hb.z & 0xffffu) << 16), acc[4]);
        acc[5] = fmaf(wb, __uint_as_float(hb.z & 0xffff0000u),     acc[5]);
        acc[6] = fmaf(wb, __uint_as_float((hb.w & 0xffffu) << 16), acc[6]);
        acc[7] = fmaf(wb, __uint_as_float(hb.w & 0xffff0000u),     acc[7]);
    }

    // rare overflow edges folded in (entry i handled by lane-group i&3)
    if (degf > MAXD) {
        int n = flag[1]; if (n > OVF_CAP) n = OVF_CAP;
        for (int i = 0; i < n; ++i) {
            int2 r = ovf[i];
            if (r.x != node || (i & 3) != grp) continue;
            unsigned rec = (unsigned)r.y;
            float w = __uint_as_float(rec & 0xffff0000u);
            unsigned src = rec & 0xffffu;
            uint4 h = *((const uint4*)(hid + (size_t)src * 64) + sub);
            acc[0] = fmaf(w, __uint_as_float((h.x & 0xffffu) << 16), acc[0]);
            acc[1] = fmaf(w, __uint_as_float(h.x & 0xffff0000u),     acc[1]);
            acc[2] = fmaf(w, __uint_as_float((h.y & 0xffffu) << 16), acc[2]);
            acc[3] = fmaf(w, __uint_as_float(h.y & 0xffff0000u),     acc[3]);
            acc[4] = fmaf(w, __uint_as_float((h.z & 0xffffu) << 16), acc[4]);
            acc[5] = fmaf(w, __uint_as_float(h.z & 0xffff0000u),     acc[5]);
            acc[6] = fmaf(w, __uint_as_float((h.w & 0xffffu) << 16), acc[6]);
            acc[7] = fmaf(w, __uint_as_float(h.w & 0xffff0000u),     acc[7]);
        }
    }

    // combine the 4 lane-groups: butterfly over lane bits 4,5
    #pragma unroll
    for (int j = 0; j < 8; ++j) {
        float a = acc[j];
        a += __shfl_xor(a, 16, 64);
        a += __shfl_xor(a, 32, 64);
        acc[j] = a;
    }

    if (lane < 16) {
        float* o = out + (size_t)node * FEAT + sub * 8;
        *(float4*)(o)     = make_float4(acc[0], acc[1], acc[2], acc[3]);
        *(float4*)(o + 4) = make_float4(acc[4], acc[5], acc[6], acc[7]);
    }
}

extern "C" void kernel_launch(void* const* d_in, const int* in_sizes, int n_in,
                              void* d_out, int out_size, void* d_ws, size_t ws_size,
                              hipStream_t stream) {
    const float* x  = (const float*)d_in[0];
    const int*   ei = (const int*)d_in[1];
    const float* ew = (const float*)d_in[2];
    const float* W  = (const float*)d_in[3];
    const float* b  = (const float*)d_in[4];
    float* out = (float*)d_out;

    int*  flag = (int*)d_ws;
    int*  fill = flag + 16;
    int2* ovf  = (int2*)(fill + 50048);
    unsigned int* slots = (unsigned int*)(ovf + OVF_CAP);
    unsigned short* hidden = (unsigned short*)(slots + (size_t)N_NODES * MAXD);
    int2* queue = (int2*)(hidden + (size_t)N_NODES * FEAT);

    // zero flag[16] (ovf + queue cursors) + fill[50048] in one DMA memset
    hipMemsetAsync(d_ws, 0, 64 + 50048 * sizeof(int), stream);

    k_fused<<<GEMM_BLOCKS + NCHUNK, 256, 0, stream>>>(x, W, b, hidden, ei, ew,
                                                      flag, queue);
    k_scat <<<8 * SCAT_BPG, 256, 0, stream>>>(flag, queue, flag, fill, slots, ovf);
    k_agg  <<<N_NODES / 4, 256, 0, stream>>>(fill, slots, (const unsigned int*)hidden,
                                             flag, ovf, out);
}

// Round 5
// 173.740 us; speedup vs baseline: 7.4669x; 7.4669x over previous
//
#include <hip/hip_runtime.h>
#include <hip/hip_bf16.h>

#define N_NODES 50000
#define N_EDGES 800000
#define FEAT    128
#define N_TILES (N_NODES / 16)          // 3125
#define GEMM_BLOCKS 784                  // 782 needed (3125/4), padded to mult of 8
#define MAXD    32                       // slots per node; Poisson(16) P(deg>=32)~1e-4
#define OVF_CAP 16384
#define NODES_PER_GRP 6250               // 50000 / 8
#define CHUNK   2048
#define NCHUNK  ((N_EDGES + CHUNK - 1) / CHUNK)   // 391
#define QCAP    110000                   // per-group queue capacity (mean 100K, sigma~300)
#define SCAT_BPG 98                      // scatter blocks per group -> 784 total

using short8  = __attribute__((ext_vector_type(8))) short;
using float4v = __attribute__((ext_vector_type(4))) float;

// ---------------- workspace layout (bytes) ----------------
// flag int[256] @0  (flag[1]=ovf cursor; flag[16+16g]=group-g queue cursor, one/line)
// fill int[50048] @1024 | ovf int2[16384] @201216 | slots uint[50000*32] @332288
// hidden ushort[50000*128] @6732288 | queue int2[8*QCAP] @19532288   total ~26.6 MB

__device__ __forceinline__ unsigned short f2b(float f) {
    __hip_bfloat16 h = __float2bfloat16(f);           // RNE
    return __builtin_bit_cast(unsigned short, h);
}

// k1: blocks [0,GEMM_BLOCKS) = GEMM (LDS-staged W, proven R1 path).
//     blocks [GEMM_BLOCKS, +NCHUNK) = partition pass: read each edge ONCE,
//     LDS-aggregate per-group counts (8 global atomics/BLOCK, padded lines —
//     R3's 100K same-line atomics was the 1.1ms serialization).
__global__ __launch_bounds__(256) void k_fused(const float* __restrict__ x,
                                               const float* __restrict__ W,
                                               const float* __restrict__ bias,
                                               unsigned short* __restrict__ hidden,
                                               const int* __restrict__ ei,
                                               const float* __restrict__ wt,
                                               int* __restrict__ flag,
                                               int2* __restrict__ queue) {
    __shared__ __align__(16) unsigned short Wlds[128 * 136];
    const int t = threadIdx.x;

    if (blockIdx.x < GEMM_BLOCKS) {
        // ---------------- GEMM path (R1-proven) ----------------
        for (int j = 0; j < 16; ++j) {
            int idx4 = j * 256 + t;
            float4v wv = *(const float4v*)(W + (size_t)idx4 * 4);
            int r = (idx4 * 4) >> 7;
            int c = (idx4 * 4) & 127;
            unsigned short* p = &Wlds[r * 136 + c];
            p[0] = f2b(wv[0]); p[1] = f2b(wv[1]); p[2] = f2b(wv[2]); p[3] = f2b(wv[3]);
        }
        __syncthreads();

        const int wave = t >> 6;
        const int lane = t & 63;
        int tile = blockIdx.x * 4 + wave;
        if (tile >= N_TILES) tile = N_TILES - 1;    // clamp: redundant work, no divergent exit
        const int rowBase = tile * 16;
        const int m    = lane & 15;
        const int quad = lane >> 4;

        float4v acc[8];
        #pragma unroll
        for (int i = 0; i < 8; ++i) acc[i] = (float4v){0.f, 0.f, 0.f, 0.f};

        for (int kk = 0; kk < 4; ++kk) {
            const int k0 = kk * 32 + quad * 8;
            const float* ap = x + (size_t)(rowBase + m) * FEAT + k0;
            float4v a0 = *(const float4v*)(ap);
            float4v a1 = *(const float4v*)(ap + 4);
            short8 af;
            #pragma unroll
            for (int j = 0; j < 4; ++j) { af[j] = (short)f2b(a0[j]); af[4 + j] = (short)f2b(a1[j]); }
            #pragma unroll
            for (int nt = 0; nt < 8; ++nt) {
                short8 bf = *(const short8*)&Wlds[(nt * 16 + m) * 136 + k0];
                acc[nt] = __builtin_amdgcn_mfma_f32_16x16x32_bf16(af, bf, acc[nt], 0, 0, 0);
            }
        }

        const int r0 = rowBase + quad * 4;          // C/D: col=lane&15, row=quad*4+r
        for (int nt = 0; nt < 8; ++nt) {
            const int col = nt * 16 + m;
            const float bc = bias[col];
            #pragma unroll
            for (int r = 0; r < 4; ++r) {
                hidden[(size_t)(r0 + r) * FEAT + col] = f2b(acc[nt][r] + bc);
            }
        }
    } else {
        // ---------------- partition pass (LDS-aggregated) ----------------
        int* lcnt  = (int*)Wlds;                     // [8] per-group local counts
        int* gbase = lcnt + 8;                       // [8] per-group global bases
        const int bid  = blockIdx.x - GEMM_BLOCKS;   // chunk id, 0..390
        const int lane = t & 63;

        // per-wave int64-vs-int32 detection (int64: odd words of first 64 are 0)
        unsigned long long mball = __ballot(ei[2 * lane + 1] != 0);
        const int sh = (mball == 0ULL) ? 1 : 0;

        if (t < 8) lcnt[t] = 0;
        __syncthreads();

        const int e0 = bid * CHUNK + t;
        int      dstv[8];
        unsigned recv_[8];
        int      lpos[8];
        #pragma unroll
        for (int i = 0; i < 8; ++i) {
            int e = e0 + i * 256;
            if (e < N_EDGES) {
                int dst = ei[(size_t)e << sh];
                if ((unsigned)dst >= N_NODES) dst = 0;
                int src = ei[(size_t)(N_EDGES + e) << sh];
                if ((unsigned)src >= N_NODES) src = 0;
                dstv[i]  = dst;
                recv_[i] = ((unsigned)f2b(wt[e]) << 16) | (unsigned)src;
                lpos[i]  = atomicAdd(&lcnt[dst / NODES_PER_GRP], 1);
            } else {
                dstv[i] = -1;
            }
        }
        __syncthreads();
        if (t < 8) gbase[t] = atomicAdd(&flag[16 + 16 * t], lcnt[t]);
        __syncthreads();

        #pragma unroll
        for (int i = 0; i < 8; ++i) {
            if (dstv[i] < 0) continue;
            int g   = dstv[i] / NODES_PER_GRP;
            int idx = gbase[g] + lpos[i];
            if (idx < QCAP) {
                int2 r; r.x = dstv[i]; r.y = (int)recv_[i];
                queue[(size_t)g * QCAP + idx] = r;
            }
        }
    }
}

// k2: XCD-local scatter. Group g's blocks read ONLY queue[g] (~800KB, coalesced);
// fill/slot atomics+stores hit an 800KB region resident in that XCD's L2.
__global__ __launch_bounds__(256) void k_scat(const int2* __restrict__ queue,
                                              int* __restrict__ flag,
                                              int* __restrict__ fill,
                                              unsigned int* __restrict__ slots,
                                              int2* __restrict__ ovf) {
    const int g = blockIdx.x & 7;                    // == XCD (round-robin dispatch)
    const int b = blockIdx.x >> 3;                   // 0..SCAT_BPG-1
    int n = flag[16 + 16 * g]; if (n > QCAP) n = QCAP;
    const int2* q = queue + (size_t)g * QCAP;

    for (int i = b * 256 + (int)threadIdx.x; i < n; i += SCAT_BPG * 256) {
        int2 ent = q[i];
        int dst = ent.x;
        int pos = atomicAdd(&fill[dst], 1);
        if (pos < MAXD) {
            slots[(size_t)dst * MAXD + pos] = (unsigned int)ent.y;
        } else {
            int op = atomicAdd(&flag[1], 1);
            if (op < OVF_CAP) { int2 r; r.x = dst; r.y = ent.y; ovf[op] = r; }
        }
    }
}

// out[node][:] = sum_slots w_e * hidden[src_e][:]
// wave per node; lane-group g (16 lanes) handles edge e+g; each lane loads 16B
// (8 bf16 feats). 2x unrolled: two slot-lines + two gathers in flight.
__global__ __launch_bounds__(256) void k_agg(const int* __restrict__ fill,
                                             const unsigned int* __restrict__ slots,
                                             const unsigned int* __restrict__ hid,
                                             const int* __restrict__ flag,
                                             const int2* __restrict__ ovf,
                                             float* __restrict__ out) {
    const int wave = threadIdx.x >> 6;
    const int lane = threadIdx.x & 63;
    const int node = blockIdx.x * 4 + wave;         // grid exact: 12500*4 = 50000
    const int grp  = lane >> 4;
    const int sub  = lane & 15;

    const int degf = fill[node];
    const int deg  = (degf > MAXD) ? MAXD : degf;
    const uint4* sl4 = (const uint4*)(slots + (size_t)node * MAXD);  // 8 lines

    float acc[8];
    #pragma unroll
    for (int j = 0; j < 8; ++j) acc[j] = 0.f;

    const int iters = (deg + 3) >> 2;               // <= 8
    for (int it = 0; it < iters; it += 2) {
        uint4 ra = sl4[it];
        uint4 rb = sl4[it | 1];                     // <=7: always in-bounds
        unsigned reca = (grp < 2) ? (grp == 0 ? ra.x : ra.y)
                                  : (grp == 2 ? ra.z : ra.w);
        unsigned recb = (grp < 2) ? (grp == 0 ? rb.x : rb.y)
                                  : (grp == 2 ? rb.z : rb.w);
        const int  ea = it * 4 + grp;
        const int  eb = ea + 4;
        const bool va = ea < deg;
        const bool vb = eb < deg;
        const float wa = va ? __uint_as_float(reca & 0xffff0000u) : 0.f;
        const float wb = vb ? __uint_as_float(recb & 0xffff0000u) : 0.f;
        const unsigned sa = va ? (reca & 0xffffu) : 0u;
        const unsigned sb = vb ? (recb & 0xffffu) : 0u;
        uint4 ha = *((const uint4*)(hid + (size_t)sa * 64) + sub);  // 16B/lane gather
        uint4 hb = *((const uint4*)(hid + (size_t)sb * 64) + sub);
        acc[0] = fmaf(wa, __uint_as_float((ha.x & 0xffffu) << 16), acc[0]);
        acc[1] = fmaf(wa, __uint_as_float(ha.x & 0xffff0000u),     acc[1]);
        acc[2] = fmaf(wa, __uint_as_float((ha.y & 0xffffu) << 16), acc[2]);
        acc[3] = fmaf(wa, __uint_as_float(ha.y & 0xffff0000u),     acc[3]);
        acc[4] = fmaf(wa, __uint_as_float((ha.z & 0xffffu) << 16), acc[4]);
        acc[5] = fmaf(wa, __uint_as_float(ha.z & 0xffff0000u),     acc[5]);
        acc[6] = fmaf(wa, __uint_as_float((ha.w & 0xffffu) << 16), acc[6]);
        acc[7] = fmaf(wa, __uint_as_float(ha.w & 0xffff0000u),     acc[7]);
        acc[0] = fmaf(wb, __uint_as_float((hb.x & 0xffffu) << 16), acc[0]);
        acc[1] = fmaf(wb, __uint_as_float(hb.x & 0xffff0000u),     acc[1]);
        acc[2] = fmaf(wb, __uint_as_float((hb.y & 0xffffu) << 16), acc[2]);
        acc[3] = fmaf(wb, __uint_as_float(hb.y & 0xffff0000u),     acc[3]);
        acc[4] = fmaf(wb, __uint_as_float((hb.z & 0xffffu) << 16), acc[4]);
        acc[5] = fmaf(wb, __uint_as_float(hb.z & 0xffff0000u),     acc[5]);
        acc[6] = fmaf(wb, __uint_as_float((hb.w & 0xffffu) << 16), acc[6]);
        acc[7] = fmaf(wb, __uint_as_float(hb.w & 0xffff0000u),     acc[7]);
    }

    // rare overflow edges folded in (entry i handled by lane-group i&3)
    if (degf > MAXD) {
        int n = flag[1]; if (n > OVF_CAP) n = OVF_CAP;
        for (int i = 0; i < n; ++i) {
            int2 r = ovf[i];
            if (r.x != node || (i & 3) != grp) continue;
            unsigned rec = (unsigned)r.y;
            float w = __uint_as_float(rec & 0xffff0000u);
            unsigned src = rec & 0xffffu;
            uint4 h = *((const uint4*)(hid + (size_t)src * 64) + sub);
            acc[0] = fmaf(w, __uint_as_float((h.x & 0xffffu) << 16), acc[0]);
            acc[1] = fmaf(w, __uint_as_float(h.x & 0xffff0000u),     acc[1]);
            acc[2] = fmaf(w, __uint_as_float((h.y & 0xffffu) << 16), acc[2]);
            acc[3] = fmaf(w, __uint_as_float(h.y & 0xffff0000u),     acc[3]);
            acc[4] = fmaf(w, __uint_as_float((h.z & 0xffffu) << 16), acc[4]);
            acc[5] = fmaf(w, __uint_as_float(h.z & 0xffff0000u),     acc[5]);
            acc[6] = fmaf(w, __uint_as_float((h.w & 0xffffu) << 16), acc[6]);
            acc[7] = fmaf(w, __uint_as_float(h.w & 0xffff0000u),     acc[7]);
        }
    }

    // combine the 4 lane-groups: butterfly over lane bits 4,5
    #pragma unroll
    for (int j = 0; j < 8; ++j) {
        float a = acc[j];
        a += __shfl_xor(a, 16, 64);
        a += __shfl_xor(a, 32, 64);
        acc[j] = a;
    }

    if (lane < 16) {
        float* o = out + (size_t)node * FEAT + sub * 8;
        *(float4*)(o)     = make_float4(acc[0], acc[1], acc[2], acc[3]);
        *(float4*)(o + 4) = make_float4(acc[4], acc[5], acc[6], acc[7]);
    }
}

extern "C" void kernel_launch(void* const* d_in, const int* in_sizes, int n_in,
                              void* d_out, int out_size, void* d_ws, size_t ws_size,
                              hipStream_t stream) {
    const float* x  = (const float*)d_in[0];
    const int*   ei = (const int*)d_in[1];
    const float* ew = (const float*)d_in[2];
    const float* W  = (const float*)d_in[3];
    const float* b  = (const float*)d_in[4];
    float* out = (float*)d_out;

    int*  flag = (int*)d_ws;                          // int[256], cursors padded
    int*  fill = flag + 256;
    int2* ovf  = (int2*)(fill + 50048);
    unsigned int* slots = (unsigned int*)(ovf + OVF_CAP);
    unsigned short* hidden = (unsigned short*)(slots + (size_t)N_NODES * MAXD);
    int2* queue = (int2*)(hidden + (size_t)N_NODES * FEAT);

    // zero flag[256] (ovf + padded queue cursors) + fill[50048] in one DMA memset
    hipMemsetAsync(d_ws, 0, 256 * sizeof(int) + 50048 * sizeof(int), stream);

    k_fused<<<GEMM_BLOCKS + NCHUNK, 256, 0, stream>>>(x, W, b, hidden, ei, ew,
                                                      flag, queue);
    k_scat <<<8 * SCAT_BPG, 256, 0, stream>>>(queue, flag, fill, slots, ovf);
    k_agg  <<<N_NODES / 4, 256, 0, stream>>>(fill, slots, (const unsigned int*)hidden,
                                             flag, ovf, out);
}

// Round 6
// 166.274 us; speedup vs baseline: 7.8022x; 1.0449x over previous
//
#include <hip/hip_runtime.h>
#include <hip/hip_bf16.h>

#define N_NODES 50000
#define N_EDGES 800000
#define FEAT    128
#define N_TILES (N_NODES / 16)          // 3125
#define GEMM_BLOCKS 784                  // 782 needed (3125/4), padded to mult of 8
#define MAXD    32                       // slots per node; Poisson(16) P(deg>=32)~1e-4
#define OVF_CAP 16384
#define NODES_PER_GRP 6250               // 50000 / 8
#define CHUNK   2048
#define NCHUNK  ((N_EDGES + CHUNK - 1) / CHUNK)   // 391
#define QCAP    110000                   // per-group queue capacity (mean 100K, sigma~300)
#define SCAT_BPG 98                      // scatter blocks per group -> 784 total

using short8  = __attribute__((ext_vector_type(8))) short;
using float4v = __attribute__((ext_vector_type(4))) float;

// ---------------- workspace layout (bytes) ----------------
// flag int[256] @0  (flag[1]=ovf cursor; flag[16+16g]=group-g queue cursor, one/line)
// fill int[50048] @1024 | ovf int2[16384] @201216 | slots uint[50000*32] @332288
// hidden ushort[50000*128] @6732288 | queue int2[8*QCAP] @19532288   total ~26.6 MB

__device__ __forceinline__ unsigned short f2b(float f) {
    __hip_bfloat16 h = __float2bfloat16(f);           // RNE
    return __builtin_bit_cast(unsigned short, h);
}

// k1: blocks [0,GEMM_BLOCKS) = GEMM (LDS-staged W). kk-loop fully unrolled for
//     load-latency ILP. blocks [GEMM_BLOCKS, +NCHUNK) = partition pass: read
//     each edge ONCE, LDS-aggregate per-group counts (8 global atomics/BLOCK
//     on padded lines — R3's 100K same-line atomics was the 1.1ms lesson).
__global__ __launch_bounds__(256) void k_fused(const float* __restrict__ x,
                                               const float* __restrict__ W,
                                               const float* __restrict__ bias,
                                               unsigned short* __restrict__ hidden,
                                               const int* __restrict__ ei,
                                               const float* __restrict__ wt,
                                               int* __restrict__ flag,
                                               int2* __restrict__ queue) {
    __shared__ __align__(16) unsigned short Wlds[128 * 136];
    const int t = threadIdx.x;

    if (blockIdx.x < GEMM_BLOCKS) {
        // ---------------- GEMM path ----------------
        for (int j = 0; j < 16; ++j) {
            int idx4 = j * 256 + t;
            float4v wv = *(const float4v*)(W + (size_t)idx4 * 4);
            int r = (idx4 * 4) >> 7;
            int c = (idx4 * 4) & 127;
            unsigned short* p = &Wlds[r * 136 + c];
            p[0] = f2b(wv[0]); p[1] = f2b(wv[1]); p[2] = f2b(wv[2]); p[3] = f2b(wv[3]);
        }
        __syncthreads();

        const int wave = t >> 6;
        const int lane = t & 63;
        int tile = blockIdx.x * 4 + wave;
        if (tile >= N_TILES) tile = N_TILES - 1;    // clamp: redundant work, no divergent exit
        const int rowBase = tile * 16;
        const int m    = lane & 15;
        const int quad = lane >> 4;

        float4v acc[8];
        #pragma unroll
        for (int i = 0; i < 8; ++i) acc[i] = (float4v){0.f, 0.f, 0.f, 0.f};

        #pragma unroll
        for (int kk = 0; kk < 4; ++kk) {
            const int k0 = kk * 32 + quad * 8;
            const float* ap = x + (size_t)(rowBase + m) * FEAT + k0;
            float4v a0 = *(const float4v*)(ap);
            float4v a1 = *(const float4v*)(ap + 4);
            short8 af;
            #pragma unroll
            for (int j = 0; j < 4; ++j) { af[j] = (short)f2b(a0[j]); af[4 + j] = (short)f2b(a1[j]); }
            #pragma unroll
            for (int nt = 0; nt < 8; ++nt) {
                short8 bf = *(const short8*)&Wlds[(nt * 16 + m) * 136 + k0];
                acc[nt] = __builtin_amdgcn_mfma_f32_16x16x32_bf16(af, bf, acc[nt], 0, 0, 0);
            }
        }

        const int r0 = rowBase + quad * 4;          // C/D: col=lane&15, row=quad*4+r
        #pragma unroll
        for (int nt = 0; nt < 8; ++nt) {
            const int col = nt * 16 + m;
            const float bc = bias[col];
            #pragma unroll
            for (int r = 0; r < 4; ++r) {
                hidden[(size_t)(r0 + r) * FEAT + col] = f2b(acc[nt][r] + bc);
            }
        }
    } else {
        // ---------------- partition pass (LDS-aggregated) ----------------
        int* lcnt  = (int*)Wlds;                     // [8] per-group local counts
        int* gbase = lcnt + 8;                       // [8] per-group global bases
        const int bid  = blockIdx.x - GEMM_BLOCKS;   // chunk id, 0..390
        const int lane = t & 63;

        // per-wave int64-vs-int32 detection (int64: odd words of first 64 are 0)
        unsigned long long mball = __ballot(ei[2 * lane + 1] != 0);
        const int sh = (mball == 0ULL) ? 1 : 0;

        if (t < 8) lcnt[t] = 0;
        __syncthreads();

        const int e0 = bid * CHUNK + t;
        int      dstv[8];
        unsigned recv_[8];
        int      lpos[8];
        #pragma unroll
        for (int i = 0; i < 8; ++i) {
            int e = e0 + i * 256;
            if (e < N_EDGES) {
                int dst = ei[(size_t)e << sh];
                if ((unsigned)dst >= N_NODES) dst = 0;
                int src = ei[(size_t)(N_EDGES + e) << sh];
                if ((unsigned)src >= N_NODES) src = 0;
                dstv[i]  = dst;
                recv_[i] = ((unsigned)f2b(wt[e]) << 16) | (unsigned)src;
                lpos[i]  = atomicAdd(&lcnt[dst / NODES_PER_GRP], 1);
            } else {
                dstv[i] = -1;
            }
        }
        __syncthreads();
        if (t < 8) gbase[t] = atomicAdd(&flag[16 + 16 * t], lcnt[t]);
        __syncthreads();

        #pragma unroll
        for (int i = 0; i < 8; ++i) {
            if (dstv[i] < 0) continue;
            int g   = dstv[i] / NODES_PER_GRP;
            int idx = gbase[g] + lpos[i];
            if (idx < QCAP) {
                int2 r; r.x = dstv[i]; r.y = (int)recv_[i];
                queue[(size_t)g * QCAP + idx] = r;
            }
        }
    }
}

// k2: XCD-local scatter. Group g's blocks read ONLY queue[g] (~800KB, coalesced);
// fill/slot atomics+stores hit an 800KB region resident in that XCD's L2.
__global__ __launch_bounds__(256) void k_scat(const int2* __restrict__ queue,
                                              int* __restrict__ flag,
                                              int* __restrict__ fill,
                                              unsigned int* __restrict__ slots,
                                              int2* __restrict__ ovf) {
    const int g = blockIdx.x & 7;                    // == XCD (round-robin dispatch)
    const int b = blockIdx.x >> 3;                   // 0..SCAT_BPG-1
    int n = flag[16 + 16 * g]; if (n > QCAP) n = QCAP;
    const int2* q = queue + (size_t)g * QCAP;

    for (int i = b * 256 + (int)threadIdx.x; i < n; i += SCAT_BPG * 256) {
        int2 ent = q[i];
        int dst = ent.x;
        int pos = atomicAdd(&fill[dst], 1);
        if (pos < MAXD) {
            slots[(size_t)dst * MAXD + pos] = (unsigned int)ent.y;
        } else {
            int op = atomicAdd(&flag[1], 1);
            if (op < OVF_CAP) { int2 r; r.x = dst; r.y = ent.y; ovf[op] = r; }
        }
    }
}

// out[node][:] = sum_slots w_e * hidden[src_e][:]
// wave per node; lane-group g (16 lanes) handles edge e+g; each lane loads 16B
// (8 bf16 feats). 4x unrolled: four slot-lines + four gathers in flight.
// Accumulation order per lane identical to the 2x version -> bit-identical out.
#define AGG_FMA(w_, h_)                                                      \
    acc[0] = fmaf(w_, __uint_as_float((h_.x & 0xffffu) << 16), acc[0]);      \
    acc[1] = fmaf(w_, __uint_as_float(h_.x & 0xffff0000u),     acc[1]);      \
    acc[2] = fmaf(w_, __uint_as_float((h_.y & 0xffffu) << 16), acc[2]);      \
    acc[3] = fmaf(w_, __uint_as_float(h_.y & 0xffff0000u),     acc[3]);      \
    acc[4] = fmaf(w_, __uint_as_float((h_.z & 0xffffu) << 16), acc[4]);      \
    acc[5] = fmaf(w_, __uint_as_float(h_.z & 0xffff0000u),     acc[5]);      \
    acc[6] = fmaf(w_, __uint_as_float((h_.w & 0xffffu) << 16), acc[6]);      \
    acc[7] = fmaf(w_, __uint_as_float(h_.w & 0xffff0000u),     acc[7]);

__global__ __launch_bounds__(256) void k_agg(const int* __restrict__ fill,
                                             const unsigned int* __restrict__ slots,
                                             const unsigned int* __restrict__ hid,
                                             const int* __restrict__ flag,
                                             const int2* __restrict__ ovf,
                                             float* __restrict__ out) {
    const int wave = threadIdx.x >> 6;
    const int lane = threadIdx.x & 63;
    const int node = blockIdx.x * 4 + wave;         // grid exact: 12500*4 = 50000
    const int grp  = lane >> 4;
    const int sub  = lane & 15;

    const int degf = fill[node];
    const int deg  = (degf > MAXD) ? MAXD : degf;
    const uint4* sl4 = (const uint4*)(slots + (size_t)node * MAXD);  // 8 lines

    float acc[8];
    #pragma unroll
    for (int j = 0; j < 8; ++j) acc[j] = 0.f;

    const int iters = (deg + 3) >> 2;               // <= 8
    for (int it = 0; it < iters; it += 4) {
        uint4 r0 = sl4[it];
        uint4 r1 = sl4[(it + 1) & 7];               // &7: always in-bounds lines
        uint4 r2 = sl4[(it + 2) & 7];
        uint4 r3 = sl4[(it + 3) & 7];
        unsigned rc0 = (grp < 2) ? (grp == 0 ? r0.x : r0.y) : (grp == 2 ? r0.z : r0.w);
        unsigned rc1 = (grp < 2) ? (grp == 0 ? r1.x : r1.y) : (grp == 2 ? r1.z : r1.w);
        unsigned rc2 = (grp < 2) ? (grp == 0 ? r2.x : r2.y) : (grp == 2 ? r2.z : r2.w);
        unsigned rc3 = (grp < 2) ? (grp == 0 ? r3.x : r3.y) : (grp == 2 ? r3.z : r3.w);
        const int e0 = it * 4 + grp;
        const bool v0 = (e0)      < deg;
        const bool v1 = (e0 + 4)  < deg;
        const bool v2 = (e0 + 8)  < deg;
        const bool v3 = (e0 + 12) < deg;
        const float w0 = v0 ? __uint_as_float(rc0 & 0xffff0000u) : 0.f;
        const float w1 = v1 ? __uint_as_float(rc1 & 0xffff0000u) : 0.f;
        const float w2 = v2 ? __uint_as_float(rc2 & 0xffff0000u) : 0.f;
        const float w3 = v3 ? __uint_as_float(rc3 & 0xffff0000u) : 0.f;
        const unsigned s0 = v0 ? (rc0 & 0xffffu) : 0u;
        const unsigned s1 = v1 ? (rc1 & 0xffffu) : 0u;
        const unsigned s2 = v2 ? (rc2 & 0xffffu) : 0u;
        const unsigned s3 = v3 ? (rc3 & 0xffffu) : 0u;
        uint4 h0 = *((const uint4*)(hid + (size_t)s0 * 64) + sub);  // 16B/lane gathers,
        uint4 h1 = *((const uint4*)(hid + (size_t)s1 * 64) + sub);  // 4 in flight
        uint4 h2 = *((const uint4*)(hid + (size_t)s2 * 64) + sub);
        uint4 h3 = *((const uint4*)(hid + (size_t)s3 * 64) + sub);
        AGG_FMA(w0, h0)
        AGG_FMA(w1, h1)
        AGG_FMA(w2, h2)
        AGG_FMA(w3, h3)
    }

    // rare overflow edges folded in (entry i handled by lane-group i&3)
    if (degf > MAXD) {
        int n = flag[1]; if (n > OVF_CAP) n = OVF_CAP;
        for (int i = 0; i < n; ++i) {
            int2 r = ovf[i];
            if (r.x != node || (i & 3) != grp) continue;
            unsigned rec = (unsigned)r.y;
            float w = __uint_as_float(rec & 0xffff0000u);
            unsigned src = rec & 0xffffu;
            uint4 h = *((const uint4*)(hid + (size_t)src * 64) + sub);
            AGG_FMA(w, h)
        }
    }

    // combine the 4 lane-groups: butterfly over lane bits 4,5
    #pragma unroll
    for (int j = 0; j < 8; ++j) {
        float a = acc[j];
        a += __shfl_xor(a, 16, 64);
        a += __shfl_xor(a, 32, 64);
        acc[j] = a;
    }

    if (lane < 16) {
        float* o = out + (size_t)node * FEAT + sub * 8;
        *(float4*)(o)     = make_float4(acc[0], acc[1], acc[2], acc[3]);
        *(float4*)(o + 4) = make_float4(acc[4], acc[5], acc[6], acc[7]);
    }
}

extern "C" void kernel_launch(void* const* d_in, const int* in_sizes, int n_in,
                              void* d_out, int out_size, void* d_ws, size_t ws_size,
                              hipStream_t stream) {
    const float* x  = (const float*)d_in[0];
    const int*   ei = (const int*)d_in[1];
    const float* ew = (const float*)d_in[2];
    const float* W  = (const float*)d_in[3];
    const float* b  = (const float*)d_in[4];
    float* out = (float*)d_out;

    int*  flag = (int*)d_ws;                          // int[256], cursors padded
    int*  fill = flag + 256;
    int2* ovf  = (int2*)(fill + 50048);
    unsigned int* slots = (unsigned int*)(ovf + OVF_CAP);
    unsigned short* hidden = (unsigned short*)(slots + (size_t)N_NODES * MAXD);
    int2* queue = (int2*)(hidden + (size_t)N_NODES * FEAT);

    // zero flag[256] (ovf + padded queue cursors) + fill[50048] in one DMA memset
    hipMemsetAsync(d_ws, 0, 256 * sizeof(int) + 50048 * sizeof(int), stream);

    k_fused<<<GEMM_BLOCKS + NCHUNK, 256, 0, stream>>>(x, W, b, hidden, ei, ew,
                                                      flag, queue);
    k_scat <<<8 * SCAT_BPG, 256, 0, stream>>>(queue, flag, fill, slots, ovf);
    k_agg  <<<N_NODES / 4, 256, 0, stream>>>(fill, slots, (const unsigned int*)hidden,
                                             flag, ovf, out);
}